// Round 1
// baseline (222.809 us; speedup 1.0000x reference)
//
#include <hip/hip_runtime.h>

typedef unsigned short u16;
typedef unsigned int u32;

typedef __bf16 bf16x8 __attribute__((ext_vector_type(8)));
typedef float f32x4 __attribute__((ext_vector_type(4)));

union FragI { int4 i; bf16x8 b; };
union FragU { bf16x8 b; u16 u[8]; };

__device__ __forceinline__ u16 f2bf(float x) {
  u32 u = __float_as_uint(x);
  u32 r = (u + 0x7fffu + ((u >> 16) & 1u)) >> 16;
  return (u16)r;
}

__device__ __forceinline__ float tanh_fast(float x) {
  // exact identity: tanh(x) = 1 - 2/(exp(2x)+1); |x| <= ~6 here, no overflow
  float e = __expf(2.0f * x);
  return 1.0f - __fdividef(2.0f, e + 1.0f);
}

__device__ __forceinline__ bf16x8 load_cvt8(const float* __restrict__ p) {
  float4 f0 = *(const float4*)p;
  float4 f1 = *(const float4*)(p + 4);
  FragU t;
  t.u[0] = f2bf(f0.x); t.u[1] = f2bf(f0.y); t.u[2] = f2bf(f0.z); t.u[3] = f2bf(f0.w);
  t.u[4] = f2bf(f1.x); t.u[5] = f2bf(f1.y); t.u[6] = f2bf(f1.z); t.u[7] = f2bf(f1.w);
  return t.b;
}

// ---------------- f32 -> bf16 conversions ----------------
__global__ __launch_bounds__(256) void conv_v4(const float* __restrict__ in,
                                               u16* __restrict__ out, int n4) {
  int i = blockIdx.x * 256 + threadIdx.x;
  if (i >= n4) return;
  float4 f = ((const float4*)in)[i];
  union { u16 u[4]; int2 v; } o;
  o.u[0] = f2bf(f.x); o.u[1] = f2bf(f.y); o.u[2] = f2bf(f.z); o.u[3] = f2bf(f.w);
  ((int2*)out)[i] = o.v;
}

// W_dur [5][640] -> padded bf16 [16][640] (rows 5..15 zero)
__global__ __launch_bounds__(256) void conv_wdur(const float* __restrict__ in,
                                                 u16* __restrict__ out) {
  int i = blockIdx.x * 256 + threadIdx.x;
  if (i < 16 * 640) out[i] = (i < 5 * 640) ? f2bf(in[i]) : (u16)0;
}

// ---------------- projection GEMM ----------------
// C[M,N] = A[M,K] @ Bw[N,K]^T + bias[N].  64x64 tile, 4 waves K-split (K % 128 == 0).
__global__ __launch_bounds__(256) void proj_gemm(const float* __restrict__ A,
                                                 const float* __restrict__ Bw,
                                                 const float* __restrict__ bias,
                                                 float* __restrict__ C,
                                                 int M, int N, int K) {
  int tid = threadIdx.x;
  int lane = tid & 63, wid = tid >> 6;
  int m0 = blockIdx.x * 64, n0 = blockIdx.y * 64;
  int kper = K >> 2;
  int kbase = wid * kper;
  int ksteps = kper >> 5;
  int r16 = lane & 15, khi = (lane >> 4) * 8;

  f32x4 z = {0.f, 0.f, 0.f, 0.f};
  f32x4 acc[4][4];
  for (int i = 0; i < 4; ++i)
    for (int j = 0; j < 4; ++j) acc[i][j] = z;

  for (int ks = 0; ks < ksteps; ++ks) {
    int k = kbase + ks * 32 + khi;
    bf16x8 af[4], bf[4];
#pragma unroll
    for (int fm = 0; fm < 4; ++fm)
      af[fm] = load_cvt8(A + (size_t)(m0 + fm * 16 + r16) * K + k);
#pragma unroll
    for (int fn = 0; fn < 4; ++fn)
      bf[fn] = load_cvt8(Bw + (size_t)(n0 + fn * 16 + r16) * K + k);
#pragma unroll
    for (int fm = 0; fm < 4; ++fm)
#pragma unroll
      for (int fn = 0; fn < 4; ++fn)
        acc[fm][fn] = __builtin_amdgcn_mfma_f32_16x16x32_bf16(af[fm], bf[fn], acc[fm][fn], 0, 0, 0);
  }

  __shared__ float red[4][64][64];  // 64 KiB
#pragma unroll
  for (int fm = 0; fm < 4; ++fm)
#pragma unroll
    for (int fn = 0; fn < 4; ++fn)
#pragma unroll
      for (int i = 0; i < 4; ++i)
        red[wid][fm * 16 + (lane >> 4) * 4 + i][fn * 16 + r16] = acc[fm][fn][i];
  __syncthreads();
  for (int idx = tid; idx < 4096; idx += 256) {
    int r = idx >> 6, c = idx & 63;
    float s = red[0][r][c] + red[1][r][c] + red[2][r][c] + red[3][r][c] + bias[n0 + c];
    C[(size_t)(m0 + r) * N + n0 + c] = s;
  }
}

// ---------------- joint = tanh(enc + pred) -> bf16 ----------------
// enc: [B*T=1024][640] f32, pred: [B*U=256][640] f32, J: [65536][640] bf16
__global__ __launch_bounds__(256) void joint_tanh(const float* __restrict__ enc,
                                                  const float* __restrict__ pred,
                                                  u16* __restrict__ J) {
  const int total = 65536 * 80;  // 8-element chunks
  for (int c = blockIdx.x * 256 + threadIdx.x; c < total; c += gridDim.x * 256) {
    int m = c / 80;
    int j = c - m * 80;
    int bt = m >> 6;
    int uu = m & 63;
    int b = bt >> 8;
    const float* ep = enc + bt * 640 + j * 8;
    const float* pp = pred + (b * 64 + uu) * 640 + j * 8;
    float4 e0 = *(const float4*)ep;
    float4 e1 = *(const float4*)(ep + 4);
    float4 p0 = *(const float4*)pp;
    float4 p1 = *(const float4*)(pp + 4);
    union { u16 u[8]; int4 v; } o;
    o.u[0] = f2bf(tanh_fast(e0.x + p0.x));
    o.u[1] = f2bf(tanh_fast(e0.y + p0.y));
    o.u[2] = f2bf(tanh_fast(e0.z + p0.z));
    o.u[3] = f2bf(tanh_fast(e0.w + p0.w));
    o.u[4] = f2bf(tanh_fast(e1.x + p1.x));
    o.u[5] = f2bf(tanh_fast(e1.y + p1.y));
    o.u[6] = f2bf(tanh_fast(e1.z + p1.z));
    o.u[7] = f2bf(tanh_fast(e1.w + p1.w));
    *(int4*)(J + (size_t)c * 8) = o.v;
  }
}

// ---------------- main GEMM: logits (+ durations on bn==0 blocks) ----------------
// J [65536][640] bf16, Wo [1024][640] bf16, Wd [16][640] bf16 (rows>=5 zero)
// out: logits f32 [65536][1024] at 0, durations f32 [65536][5] at 67108864
#define LOGITS_N 67108864
__global__ __launch_bounds__(256) void main_gemm(const u16* __restrict__ J,
                                                 const u16* __restrict__ Wo,
                                                 const u16* __restrict__ Wd,
                                                 const float* __restrict__ b_out,
                                                 const float* __restrict__ b_dur,
                                                 float* __restrict__ out) {
  __shared__ __align__(16) u16 Asm[128 * 64];
  __shared__ __align__(16) u16 Bsm[128 * 64];
  int tid = threadIdx.x;
  int lane = tid & 63, wid = tid >> 6;
  int bid = blockIdx.x;
  // XCD-aware swizzle: 4096 blocks, 8 XCDs -> contiguous bm chunks per XCD
  int swz = (bid & 7) * 512 + (bid >> 3);
  int bn = swz & 7;
  int bm = swz >> 3;
  int m0 = bm * 128, n0 = bn * 128;
  int wr = wid >> 1, wc = wid & 1;
  int r16 = lane & 15, khi = (lane >> 4) * 8;

  int stg_row = wid * 8 + (lane >> 3);  // + j*32
  int stg_col = (lane & 7) * 8;         // elements (16B chunks)

  f32x4 z = {0.f, 0.f, 0.f, 0.f};
  f32x4 acc[4][4];
  for (int i = 0; i < 4; ++i)
    for (int j = 0; j < 4; ++j) acc[i][j] = z;
  f32x4 dacc[4] = {z, z, z, z};
  bool do_dur = (bn == 0);

  for (int k0 = 0; k0 < 640; k0 += 64) {
#pragma unroll
    for (int j = 0; j < 4; ++j) {
      int r = j * 32 + stg_row;
      const u16* g = J + (size_t)(m0 + r) * 640 + k0 + stg_col;
      u16* l = Asm + (j * 4 + wid) * 512;
      __builtin_amdgcn_global_load_lds((const __attribute__((address_space(1))) u32*)g,
                                       (__attribute__((address_space(3))) u32*)l, 16, 0, 0);
    }
#pragma unroll
    for (int j = 0; j < 4; ++j) {
      int r = j * 32 + stg_row;
      const u16* g = Wo + (size_t)(n0 + r) * 640 + k0 + stg_col;
      u16* l = Bsm + (j * 4 + wid) * 512;
      __builtin_amdgcn_global_load_lds((const __attribute__((address_space(1))) u32*)g,
                                       (__attribute__((address_space(3))) u32*)l, 16, 0, 0);
    }
    __syncthreads();  // compiler drains vmcnt before s_barrier
#pragma unroll
    for (int kk = 0; kk < 64; kk += 32) {
      FragI af[4], bfr[4];
#pragma unroll
      for (int fm = 0; fm < 4; ++fm)
        af[fm].i = *(const int4*)(Asm + (wr * 64 + fm * 16 + r16) * 64 + kk + khi);
#pragma unroll
      for (int fn = 0; fn < 4; ++fn)
        bfr[fn].i = *(const int4*)(Bsm + (wc * 64 + fn * 16 + r16) * 64 + kk + khi);
#pragma unroll
      for (int fm = 0; fm < 4; ++fm)
#pragma unroll
        for (int fn = 0; fn < 4; ++fn)
          acc[fm][fn] = __builtin_amdgcn_mfma_f32_16x16x32_bf16(af[fm].b, bfr[fn].b, acc[fm][fn], 0, 0, 0);
      if (do_dur) {
        FragI bd;
        bd.i = *(const int4*)(Wd + (size_t)r16 * 640 + k0 + kk + khi);
#pragma unroll
        for (int fm = 0; fm < 4; ++fm)
          dacc[fm] = __builtin_amdgcn_mfma_f32_16x16x32_bf16(af[fm].b, bd.b, dacc[fm], 0, 0, 0);
      }
    }
    __syncthreads();
  }

  int rbase = m0 + wr * 64 + (lane >> 4) * 4;
  int cbase = n0 + wc * 64 + r16;
#pragma unroll
  for (int fn = 0; fn < 4; ++fn) {
    int col = cbase + fn * 16;
    float bo = b_out[col];
#pragma unroll
    for (int fm = 0; fm < 4; ++fm) {
      int row = rbase + fm * 16;
#pragma unroll
      for (int i = 0; i < 4; ++i)
        out[(size_t)(row + i) * 1024 + col] = acc[fm][fn][i] + bo;
    }
  }
  if (do_dur && r16 < 5) {
    float bd = b_dur[r16];
#pragma unroll
    for (int fm = 0; fm < 4; ++fm) {
      int row = rbase + fm * 16;
#pragma unroll
      for (int i = 0; i < 4; ++i)
        out[LOGITS_N + (size_t)(row + i) * 5 + r16] = dacc[fm][i] + bd;
    }
  }
}

extern "C" void kernel_launch(void* const* d_in, const int* in_sizes, int n_in,
                              void* d_out, int out_size, void* d_ws, size_t ws_size,
                              hipStream_t stream) {
  const float* encoder   = (const float*)d_in[0];
  const float* predictor = (const float*)d_in[1];
  const float* W_enc = (const float*)d_in[2];
  const float* b_enc = (const float*)d_in[3];
  const float* W_pred = (const float*)d_in[4];
  const float* b_pred = (const float*)d_in[5];
  const float* W_out = (const float*)d_in[6];
  const float* b_out = (const float*)d_in[7];
  const float* W_dur = (const float*)d_in[8];
  const float* b_dur = (const float*)d_in[9];
  float* out = (float*)d_out;

  char* ws = (char*)d_ws;
  u16* Jbuf   = (u16*)(ws);                    // 65536*640*2     = 83,886,080 B
  u16* WoutB  = (u16*)(ws + 83886080);         // 1024*640*2      =  1,310,720 B
  u16* WdurB  = (u16*)(ws + 85196800);         // 16*640*2        =     20,480 B
  float* encP = (float*)(ws + 85217280);       // 1024*640*4      =  2,621,440 B
  float* predP = (float*)(ws + 87838720);      // 256*640*4       =    655,360 B
  // total 88,494,080 B of ws

  conv_v4<<<640, 256, 0, stream>>>(W_out, WoutB, 163840);      // 1024*640/4
  conv_wdur<<<40, 256, 0, stream>>>(W_dur, WdurB);
  proj_gemm<<<dim3(16, 10), 256, 0, stream>>>(encoder, W_enc, b_enc, encP, 1024, 640, 1024);
  proj_gemm<<<dim3(4, 10), 256, 0, stream>>>(predictor, W_pred, b_pred, predP, 256, 640, 640);
  joint_tanh<<<2048, 256, 0, stream>>>(encP, predP, Jbuf);
  main_gemm<<<4096, 256, 0, stream>>>(Jbuf, WoutB, WdurB, b_out, b_dur, out);
}

// Round 2
// 201.801 us; speedup vs baseline: 1.1041x; 1.1041x over previous
//
#include <hip/hip_runtime.h>

typedef unsigned short u16;
typedef unsigned int u32;

typedef __bf16 bf16x8 __attribute__((ext_vector_type(8)));
typedef float f32x4 __attribute__((ext_vector_type(4)));

union FragI { int4 i; bf16x8 b; };
union FragU { bf16x8 b; u16 u[8]; };

__device__ __forceinline__ u16 f2bf(float x) {
  u32 u = __float_as_uint(x);
  u32 r = (u + 0x7fffu + ((u >> 16) & 1u)) >> 16;
  return (u16)r;
}

__device__ __forceinline__ float tanh_fast(float x) {
  float e = __expf(2.0f * x);
  return 1.0f - __fdividef(2.0f, e + 1.0f);
}

__device__ __forceinline__ bf16x8 load_cvt8(const float* __restrict__ p) {
  float4 f0 = *(const float4*)p;
  float4 f1 = *(const float4*)(p + 4);
  FragU t;
  t.u[0] = f2bf(f0.x); t.u[1] = f2bf(f0.y); t.u[2] = f2bf(f0.z); t.u[3] = f2bf(f0.w);
  t.u[4] = f2bf(f1.x); t.u[5] = f2bf(f1.y); t.u[6] = f2bf(f1.z); t.u[7] = f2bf(f1.w);
  return t.b;
}

#define GLDS(gptr, lptr) \
  __builtin_amdgcn_global_load_lds((const __attribute__((address_space(1))) u32*)(gptr), \
                                   (__attribute__((address_space(3))) u32*)(lptr), 16, 0, 0)

// ---------------- f32 -> bf16 conversion (W_out) ----------------
__global__ __launch_bounds__(256) void conv_v4(const float* __restrict__ in,
                                               u16* __restrict__ out, int n4) {
  int i = blockIdx.x * 256 + threadIdx.x;
  if (i >= n4) return;
  float4 f = ((const float4*)in)[i];
  union { u16 u[4]; int2 v; } o;
  o.u[0] = f2bf(f.x); o.u[1] = f2bf(f.y); o.u[2] = f2bf(f.z); o.u[3] = f2bf(f.w);
  ((int2*)out)[i] = o.v;
}

// ---------------- projection GEMM ----------------
__global__ __launch_bounds__(256) void proj_gemm(const float* __restrict__ A,
                                                 const float* __restrict__ Bw,
                                                 const float* __restrict__ bias,
                                                 float* __restrict__ C,
                                                 int M, int N, int K) {
  int tid = threadIdx.x;
  int lane = tid & 63, wid = tid >> 6;
  int m0 = blockIdx.x * 64, n0 = blockIdx.y * 64;
  int kper = K >> 2;
  int kbase = wid * kper;
  int ksteps = kper >> 5;
  int r16 = lane & 15, khi = (lane >> 4) * 8;

  f32x4 z = {0.f, 0.f, 0.f, 0.f};
  f32x4 acc[4][4];
  for (int i = 0; i < 4; ++i)
    for (int j = 0; j < 4; ++j) acc[i][j] = z;

  for (int ks = 0; ks < ksteps; ++ks) {
    int k = kbase + ks * 32 + khi;
    bf16x8 af[4], bf[4];
#pragma unroll
    for (int fm = 0; fm < 4; ++fm)
      af[fm] = load_cvt8(A + (size_t)(m0 + fm * 16 + r16) * K + k);
#pragma unroll
    for (int fn = 0; fn < 4; ++fn)
      bf[fn] = load_cvt8(Bw + (size_t)(n0 + fn * 16 + r16) * K + k);
#pragma unroll
    for (int fm = 0; fm < 4; ++fm)
#pragma unroll
      for (int fn = 0; fn < 4; ++fn)
        acc[fm][fn] = __builtin_amdgcn_mfma_f32_16x16x32_bf16(af[fm], bf[fn], acc[fm][fn], 0, 0, 0);
  }

  __shared__ float red[4][64][64];
#pragma unroll
  for (int fm = 0; fm < 4; ++fm)
#pragma unroll
    for (int fn = 0; fn < 4; ++fn)
#pragma unroll
      for (int i = 0; i < 4; ++i)
        red[wid][fm * 16 + (lane >> 4) * 4 + i][fn * 16 + r16] = acc[fm][fn][i];
  __syncthreads();
  for (int idx = tid; idx < 4096; idx += 256) {
    int r = idx >> 6, c = idx & 63;
    float s = red[0][r][c] + red[1][r][c] + red[2][r][c] + red[3][r][c] + bias[n0 + c];
    C[(size_t)(m0 + r) * N + n0 + c] = s;
  }
}

// ---------------- joint = tanh(enc + pred) -> bf16 ----------------
__global__ __launch_bounds__(256) void joint_tanh(const float* __restrict__ enc,
                                                  const float* __restrict__ pred,
                                                  u16* __restrict__ J) {
  const int total = 65536 * 80;
  for (int c = blockIdx.x * 256 + threadIdx.x; c < total; c += gridDim.x * 256) {
    int m = c / 80;
    int j = c - m * 80;
    int bt = m >> 6;
    int uu = m & 63;
    int b = bt >> 8;
    const float* ep = enc + bt * 640 + j * 8;
    const float* pp = pred + (b * 64 + uu) * 640 + j * 8;
    float4 e0 = *(const float4*)ep;
    float4 e1 = *(const float4*)(ep + 4);
    float4 p0 = *(const float4*)pp;
    float4 p1 = *(const float4*)(pp + 4);
    union { u16 u[8]; int4 v; } o;
    o.u[0] = f2bf(tanh_fast(e0.x + p0.x));
    o.u[1] = f2bf(tanh_fast(e0.y + p0.y));
    o.u[2] = f2bf(tanh_fast(e0.z + p0.z));
    o.u[3] = f2bf(tanh_fast(e0.w + p0.w));
    o.u[4] = f2bf(tanh_fast(e1.x + p1.x));
    o.u[5] = f2bf(tanh_fast(e1.y + p1.y));
    o.u[6] = f2bf(tanh_fast(e1.z + p1.z));
    o.u[7] = f2bf(tanh_fast(e1.w + p1.w));
    *(int4*)(J + (size_t)c * 8) = o.v;
  }
}

// ---------------- main GEMM: 256x256 tile, dbuf LDS, counted vmcnt ----------------
// J [65536][640] bf16, Wo [1024][640] bf16, W_dur [5][640] f32 (padded to 16 in LDS)
// out: logits f32 [65536][1024] at 0, durations f32 [65536][5] at 67108864
#define LOGITS_N 67108864

// Stage one 256x64 bf16 tile (32 KB): 4 global_load_lds x 16B per thread.
// LDS layout physical (row, pc) holds logical (row, pc ^ ((row&7)<<3))  [T2 swizzle]
__device__ __forceinline__ void stage256(const u16* __restrict__ g, u16* l,
                                         int wid, int lane) {
  int rl = wid * 8 + (lane >> 3);
  int cl = ((lane & 7) ^ (lane >> 3)) * 8;  // pre-swizzled source column
  const u16* gp = g + (size_t)rl * 640 + cl;
  u16* lp = l + wid * 512;  // wave-uniform base; HW adds lane*16B
#pragma unroll
  for (int j = 0; j < 4; ++j)
    GLDS(gp + (size_t)j * 64 * 640, lp + j * 4096);
}

__global__ __launch_bounds__(512, 2) void main_gemm(const u16* __restrict__ J,
                                                    const u16* __restrict__ Wo,
                                                    const float* __restrict__ W_dur,
                                                    const float* __restrict__ b_out,
                                                    const float* __restrict__ b_dur,
                                                    float* __restrict__ out) {
  __shared__ __align__(16) u16 As[2][16384];
  __shared__ __align__(16) u16 Bs[2][16384];
  __shared__ __align__(16) u16 Ws[10240];
  int tid = threadIdx.x;
  int lane = tid & 63, wid = tid >> 6;
  int bid = blockIdx.x;
  // XCD-aware swizzle (1024 % 8 == 0 -> simple form is bijective)
  int swz = (bid & 7) * 128 + (bid >> 3);
  int bn = swz & 3, bm = swz >> 2;
  int m0 = bm * 256, n0 = bn * 256;
  int wr = wid >> 2, wc = wid & 3;
  int r16 = lane & 15, khi = (lane >> 4) * 8;
  int xorv = (r16 & 7) << 3;
  bool do_dur = (bn == 0);

  if (do_dur) {
    for (int i = tid; i < 10240; i += 512)
      Ws[i] = (i < 3200) ? f2bf(W_dur[i]) : (u16)0;
  }

  f32x4 z = {0.f, 0.f, 0.f, 0.f};
  f32x4 acc[8][4];
#pragma unroll
  for (int i = 0; i < 8; ++i)
#pragma unroll
    for (int j = 0; j < 4; ++j) acc[i][j] = z;
  f32x4 dacc[8];
#pragma unroll
  for (int i = 0; i < 8; ++i) dacc[i] = z;

  const u16* Jb = J + (size_t)m0 * 640;
  const u16* Wb = Wo + (size_t)n0 * 640;
  // prologue: stage tiles 0 and 1 (16 loads outstanding)
  stage256(Jb + 0, As[0], wid, lane);
  stage256(Wb + 0, Bs[0], wid, lane);
  stage256(Jb + 64, As[1], wid, lane);
  stage256(Wb + 64, Bs[1], wid, lane);
  asm volatile("s_waitcnt lgkmcnt(0)" ::: "memory");  // Ws ds_writes drained

#pragma unroll
  for (int t = 0; t < 10; ++t) {
    const int p = t & 1;
    if (t < 9) {
      asm volatile("s_waitcnt vmcnt(8)" ::: "memory");  // tile t landed; t+1 in flight
    } else {
      asm volatile("s_waitcnt vmcnt(0)" ::: "memory");
    }
    __builtin_amdgcn_sched_barrier(0);
    __builtin_amdgcn_s_barrier();
    __builtin_amdgcn_sched_barrier(0);
    const u16* Ab = As[p];
    const u16* Bb = Bs[p];
#pragma unroll
    for (int ks = 0; ks < 2; ++ks) {
      int cks = (ks * 32 + khi) ^ xorv;
      FragI bfr[4], af[8], wd;
#pragma unroll
      for (int fn = 0; fn < 4; ++fn)
        bfr[fn].i = *(const int4*)(Bb + (wc * 64 + fn * 16 + r16) * 64 + cks);
#pragma unroll
      for (int fm = 0; fm < 8; ++fm)
        af[fm].i = *(const int4*)(Ab + (wr * 128 + fm * 16 + r16) * 64 + cks);
      if (do_dur)
        wd.i = *(const int4*)(Ws + r16 * 640 + t * 64 + ks * 32 + khi);
      __builtin_amdgcn_s_setprio(1);
#pragma unroll
      for (int fm = 0; fm < 8; ++fm) {
#pragma unroll
        for (int fn = 0; fn < 4; ++fn)
          acc[fm][fn] = __builtin_amdgcn_mfma_f32_16x16x32_bf16(af[fm].b, bfr[fn].b, acc[fm][fn], 0, 0, 0);
        if (do_dur)
          dacc[fm] = __builtin_amdgcn_mfma_f32_16x16x32_bf16(af[fm].b, wd.b, dacc[fm], 0, 0, 0);
      }
      __builtin_amdgcn_s_setprio(0);
    }
    if (t < 9) {
      __builtin_amdgcn_sched_barrier(0);
      asm volatile("s_waitcnt lgkmcnt(0)" ::: "memory");  // own ds_reads done
      __builtin_amdgcn_s_barrier();                       // all waves done with buf p
      __builtin_amdgcn_sched_barrier(0);
      if (t + 2 < 10) {
        stage256(Jb + (t + 2) * 64, As[p], wid, lane);
        stage256(Wb + (t + 2) * 64, Bs[p], wid, lane);
      }
    }
  }

  // epilogue
  int rb = m0 + wr * 128 + (lane >> 4) * 4;
  int cb = n0 + wc * 64 + r16;
#pragma unroll
  for (int fn = 0; fn < 4; ++fn) {
    int col = cb + fn * 16;
    float bo = b_out[col];
#pragma unroll
    for (int fm = 0; fm < 8; ++fm) {
      int row = rb + fm * 16;
#pragma unroll
      for (int i = 0; i < 4; ++i)
        out[(size_t)(row + i) * 1024 + col] = acc[fm][fn][i] + bo;
    }
  }
  if (do_dur && r16 < 5) {
    float bd = b_dur[r16];
#pragma unroll
    for (int fm = 0; fm < 8; ++fm) {
      int row = rb + fm * 16;
#pragma unroll
      for (int i = 0; i < 4; ++i)
        out[LOGITS_N + (size_t)(row + i) * 5 + r16] = dacc[fm][i] + bd;
    }
  }
}

extern "C" void kernel_launch(void* const* d_in, const int* in_sizes, int n_in,
                              void* d_out, int out_size, void* d_ws, size_t ws_size,
                              hipStream_t stream) {
  const float* encoder   = (const float*)d_in[0];
  const float* predictor = (const float*)d_in[1];
  const float* W_enc = (const float*)d_in[2];
  const float* b_enc = (const float*)d_in[3];
  const float* W_pred = (const float*)d_in[4];
  const float* b_pred = (const float*)d_in[5];
  const float* W_out = (const float*)d_in[6];
  const float* b_out = (const float*)d_in[7];
  const float* W_dur = (const float*)d_in[8];
  const float* b_dur = (const float*)d_in[9];
  float* out = (float*)d_out;

  char* ws = (char*)d_ws;
  u16* Jbuf    = (u16*)(ws);                   // 65536*640*2 = 83,886,080 B
  u16* WoutB   = (u16*)(ws + 83886080);        // 1024*640*2  =  1,310,720 B
  float* encP  = (float*)(ws + 85196800);      // 1024*640*4  =  2,621,440 B
  float* predP = (float*)(ws + 87818240);      // 256*640*4   =    655,360 B

  conv_v4<<<640, 256, 0, stream>>>(W_out, WoutB, 163840);
  proj_gemm<<<dim3(16, 10), 256, 0, stream>>>(encoder, W_enc, b_enc, encP, 1024, 640, 1024);
  proj_gemm<<<dim3(4, 10), 256, 0, stream>>>(predictor, W_pred, b_pred, predP, 256, 640, 640);
  joint_tanh<<<2048, 256, 0, stream>>>(encP, predP, Jbuf);
  main_gemm<<<1024, 512, 0, stream>>>(Jbuf, WoutB, W_dur, b_out, b_dur, out);
}